// Round 1
// baseline (19.070 us; speedup 1.0000x reference)
//
#include <hip/hip_runtime.h>
#include <hip/hip_bf16.h>

#define IMG_H 384
#define IMG_W 384
#define KSZ 9
#define KR 4            // k//2
#define TILE 16
#define TIN (TILE + 2*KR)   // 24
#define LDS_STRIDE (TIN + 1) // 25, breaks power-of-2 bank pattern

__global__ __launch_bounds__(256) void abf_kernel(
    const float* __restrict__ input,   // [2][3][384][384]
    const float* __restrict__ sigmas,  // [2][2][384][384]
    float* __restrict__ out)           // [2][3][384][384]
{
    __shared__ float s_in[3][TIN][LDS_STRIDE];

    const int b      = blockIdx.z;
    const int tile_x = blockIdx.x * TILE;
    const int tile_y = blockIdx.y * TILE;
    const int tx     = threadIdx.x;   // 0..15
    const int ty     = threadIdx.y;   // 0..15
    const int tid    = ty * TILE + tx;

    // ---- stage 24x24x3 halo tile (zero padding outside image) ----
    const float* inb = input + (size_t)b * 3 * IMG_H * IMG_W;
    for (int i = tid; i < 3 * TIN * TIN; i += 256) {
        int c   = i / (TIN * TIN);
        int rem = i - c * (TIN * TIN);
        int ly  = rem / TIN;
        int lx  = rem - ly * TIN;
        int gy  = tile_y + ly - KR;
        int gx  = tile_x + lx - KR;
        float v = 0.0f;
        if (gy >= 0 && gy < IMG_H && gx >= 0 && gx < IMG_W)
            v = inb[c * IMG_H * IMG_W + gy * IMG_W + gx];
        s_in[c][ly][lx] = v;
    }
    __syncthreads();

    const int ox = tile_x + tx;  // 384 % 16 == 0 -> always in bounds
    const int oy = tile_y + ty;

    const float* sgb = sigmas + (size_t)b * 2 * IMG_H * IMG_W;
    float sg0 = sgb[0 * IMG_H * IMG_W + oy * IMG_W + ox];
    float sg1 = sgb[1 * IMG_H * IMG_W + oy * IMG_W + ox];
    float sig_s = 1.0f / (fabsf(sg0) + 1e-12f);
    float sig_r = 1.0f / (fabsf(sg1) + 1e-12f);
    float ss2 = sig_s * sig_s;
    float sr2 = sig_r * sig_r;

    const float c0 = s_in[0][ty + KR][tx + KR];
    const float c1 = s_in[1][ty + KR][tx + KR];
    const float c2 = s_in[2][ty + KR][tx + KR];

    float acc0 = 0.0f, acc1 = 0.0f, acc2 = 0.0f, wsum = 0.0f;

    #pragma unroll
    for (int dy = 0; dy < KSZ; ++dy) {
        const float ry = (float)(dy - KR);
        const float sy = -0.5f * ry * ry;
        #pragma unroll
        for (int dx = 0; dx < KSZ; ++dx) {
            const float rx = (float)(dx - KR);
            const float sarg = (sy - 0.5f * rx * rx) * ss2;
            float v0 = s_in[0][ty + dy][tx + dx];
            float v1 = s_in[1][ty + dy][tx + dx];
            float v2 = s_in[2][ty + dy][tx + dx];
            float d0 = v0 - c0, d1 = v1 - c1, d2 = v2 - c2;
            float dsq = fmaf(d0, d0, fmaf(d1, d1, d2 * d2));
            float w = __expf(fmaf(-0.5f * dsq, sr2, sarg));
            wsum += w;
            acc0 = fmaf(w, v0, acc0);
            acc1 = fmaf(w, v1, acc1);
            acc2 = fmaf(w, v2, acc2);
        }
    }

    const float inv = 1.0f / wsum;  // wsum >= 1 (center tap weight == 1)
    float* outb = out + (size_t)b * 3 * IMG_H * IMG_W;
    outb[0 * IMG_H * IMG_W + oy * IMG_W + ox] = acc0 * inv;
    outb[1 * IMG_H * IMG_W + oy * IMG_W + ox] = acc1 * inv;
    outb[2 * IMG_H * IMG_W + oy * IMG_W + ox] = acc2 * inv;
}

extern "C" void kernel_launch(void* const* d_in, const int* in_sizes, int n_in,
                              void* d_out, int out_size, void* d_ws, size_t ws_size,
                              hipStream_t stream) {
    const float* input  = (const float*)d_in[0];
    const float* sigmas = (const float*)d_in[1];
    float* out = (float*)d_out;

    dim3 block(TILE, TILE, 1);
    dim3 grid(IMG_W / TILE, IMG_H / TILE, 2);
    abf_kernel<<<grid, block, 0, stream>>>(input, sigmas, out);
}